// Round 1
// baseline (297.223 us; speedup 1.0000x reference)
//
#include <hip/hip_runtime.h>
#include <math.h>

#define NIN 64
#define CAP 16
#define GSEG 250
#define POOL_SPLIT 16

__device__ __forceinline__ float wave_reduce_sum(float v) {
    #pragma unroll
    for (int off = 32; off > 0; off >>= 1) v += __shfl_xor(v, off);
    return v;
}

// init: agg = 0, deg = 1 (self-loop weight), cnt = 0, graph bounds = 0
__global__ void k_init(float* __restrict__ agg, float* __restrict__ deg,
                       int* __restrict__ cnt, int* __restrict__ gstart,
                       int* __restrict__ gend, int n) {
    int i = blockIdx.x * blockDim.x + threadIdx.x;
    if (i < n * NIN) agg[i] = 0.0f;
    if (i < n) { deg[i] = 1.0f; cnt[i] = 0; }
    if (i < GSEG) { gstart[i] = 0; gend[i] = 0; }
}

__global__ void k_deg(const int* __restrict__ col, const float* __restrict__ ew,
                      float* __restrict__ deg, int e) {
    int i = blockIdx.x * blockDim.x + threadIdx.x;
    if (i < e) atomicAdd(&deg[col[i]], ew[i]);
}

__global__ void k_dinv(float* __restrict__ deg, int n) {
    int i = blockIdx.x * blockDim.x + threadIdx.x;
    if (i < n) deg[i] = rsqrtf(deg[i]);   // deg >= 1 always
}

// Build ELL lists keyed by destination (col). Overflow edges scatter directly
// into agg (agg already zeroed; gather kernel later adds on top).
__global__ void k_fill(const int* __restrict__ row, const int* __restrict__ col,
                       const float* __restrict__ ew, const float* __restrict__ dinv,
                       int* __restrict__ cnt, int* __restrict__ ell_row,
                       float* __restrict__ ell_w, float* __restrict__ agg,
                       const float* __restrict__ x, int e) {
    int i = blockIdx.x * blockDim.x + threadIdx.x;
    if (i >= e) return;
    int r = row[i], c = col[i];
    float w = dinv[r] * ew[i] * dinv[c];
    int slot = atomicAdd(&cnt[c], 1);
    if (slot < CAP) {
        ell_row[(size_t)c * CAP + slot] = r;
        ell_w[(size_t)c * CAP + slot] = w;
    } else {
        const float* xr = x + (size_t)r * NIN;
        float* ag = agg + (size_t)c * NIN;
        for (int j = 0; j < NIN; ++j) atomicAdd(&ag[j], w * xr[j]);
    }
}

__global__ void k_bounds(const int* __restrict__ seg, int* __restrict__ gstart,
                         int* __restrict__ gend, int n) {
    int i = blockIdx.x * blockDim.x + threadIdx.x;
    if (i >= n) return;
    int s = seg[i];
    if (i == 0 || seg[i - 1] != s) gstart[s] = i;
    if (i == n - 1 || seg[i + 1] != s) gend[s] = i + 1;
}

// One wave per node: agg[c] = dinv^2 * x[c] + sum_k w_k * x[r_k]  (+ overflow already in agg)
// Fused: score[c] = dot(agg[c], W_pool) + b_pool
__global__ void __launch_bounds__(256)
k_gather(const float* __restrict__ x, const float* __restrict__ dinv,
         const int* __restrict__ cnt, const int* __restrict__ ell_row,
         const float* __restrict__ ell_w, float* __restrict__ agg,
         const float* __restrict__ Wp, const float* __restrict__ bp,
         float* __restrict__ score, int n) {
    int wave = (int)((blockIdx.x * (size_t)blockDim.x + threadIdx.x) >> 6);
    int lane = threadIdx.x & 63;
    if (wave >= n) return;
    int c = wave;
    float di = dinv[c];
    float acc = di * di * x[(size_t)c * NIN + lane];
    int m = cnt[c]; if (m > CAP) m = CAP;
    const int* er = ell_row + (size_t)c * CAP;
    const float* ewl = ell_w + (size_t)c * CAP;
    for (int k = 0; k < m; ++k) {
        int r = er[k];
        float w = ewl[k];
        acc += w * x[(size_t)r * NIN + lane];
    }
    float* ag = agg + (size_t)c * NIN;
    acc += ag[lane];          // overflow contributions
    ag[lane] = acc;
    float v = wave_reduce_sum(acc * Wp[lane]);
    if (lane == 0) score[c] = v + bp[0];
}

// One block (256 thr) per graph: stable softmax over its node range; also zero out rows.
__global__ void __launch_bounds__(256)
k_softmax(const float* __restrict__ score, const int* __restrict__ gstart,
          const int* __restrict__ gend, float* __restrict__ ebuf,
          float* __restrict__ out) {
    int g = blockIdx.x;
    int s = gstart[g], e = gend[g];
    int tid = threadIdx.x;
    __shared__ float red[4];
    __shared__ float bcast;
    if (tid < NIN) out[(size_t)g * NIN + tid] = 0.0f;

    float mx = -3.402823466e38f;
    for (int i = s + tid; i < e; i += blockDim.x) mx = fmaxf(mx, score[i]);
    #pragma unroll
    for (int off = 32; off > 0; off >>= 1) mx = fmaxf(mx, __shfl_xor(mx, off));
    if ((tid & 63) == 0) red[tid >> 6] = mx;
    __syncthreads();
    if (tid == 0) bcast = fmaxf(fmaxf(red[0], red[1]), fmaxf(red[2], red[3]));
    __syncthreads();
    float m = bcast;

    float sm = 0.0f;
    for (int i = s + tid; i < e; i += blockDim.x) {
        float ev = __expf(score[i] - m);
        ebuf[i] = ev;
        sm += ev;
    }
    sm = wave_reduce_sum(sm);
    __syncthreads();
    if ((tid & 63) == 0) red[tid >> 6] = sm;
    __syncthreads();
    if (tid == 0) bcast = red[0] + red[1] + red[2] + red[3];
    __syncthreads();
    float z = bcast;
    float inv = (z > 0.0f) ? 1.0f / z : 0.0f;
    for (int i = s + tid; i < e; i += blockDim.x) ebuf[i] *= inv;
}

// POOL_SPLIT blocks per graph; wave per node-slice; per-lane W_embed column in VGPRs.
// out[g][j] += sum_n s[n] * relu( dot(agg[n], W_embed[:,j]) + b[j] )
__global__ void __launch_bounds__(256)
k_pool(const float* __restrict__ agg, const float* __restrict__ ebuf,
       const float* __restrict__ We, const float* __restrict__ be,
       const int* __restrict__ gstart, const int* __restrict__ gend,
       float* __restrict__ out) {
    int g = blockIdx.x / POOL_SPLIT;
    int p = blockIdx.x % POOL_SPLIT;
    int tid = threadIdx.x;
    int wv = tid >> 6, lane = tid & 63;

    float wcol[NIN];
    #pragma unroll
    for (int k = 0; k < NIN; ++k) wcol[k] = We[k * NIN + lane];
    float bj = be[lane];

    __shared__ float part[4][NIN];
    int s = gstart[g], e = gend[g];
    float acc = 0.0f;
    for (int n = s + p * 4 + wv; n < e; n += POOL_SPLIT * 4) {
        float a = agg[(size_t)n * NIN + lane];
        float sw = ebuf[n];
        float emb = bj;
        #pragma unroll
        for (int k = 0; k < NIN; ++k) emb += __shfl(a, k) * wcol[k];
        emb = fmaxf(emb, 0.0f);
        acc += sw * emb;
    }
    part[wv][lane] = acc;
    __syncthreads();
    if (wv == 0) {
        float r = part[0][lane] + part[1][lane] + part[2][lane] + part[3][lane];
        atomicAdd(&out[(size_t)g * NIN + lane], r);
    }
}

extern "C" void kernel_launch(void* const* d_in, const int* in_sizes, int n_in,
                              void* d_out, int out_size, void* d_ws, size_t ws_size,
                              hipStream_t stream) {
    const float* x  = (const float*)d_in[0];
    const float* We = (const float*)d_in[1];
    const float* be = (const float*)d_in[2];
    const float* Wp = (const float*)d_in[3];
    const float* bp = (const float*)d_in[4];
    const float* ew = (const float*)d_in[5];
    const int* eidx = (const int*)d_in[6];
    const int* seg  = (const int*)d_in[7];

    int N = in_sizes[0] / NIN;
    int E = in_sizes[5];
    const int* row = eidx;
    const int* col = eidx + E;

    char* w = (char*)d_ws;
    auto alloc = [&](size_t bytes) {
        char* p = w;
        w += (bytes + 255) & ~(size_t)255;
        return p;
    };
    float* agg     = (float*)alloc((size_t)N * NIN * sizeof(float));
    float* deg     = (float*)alloc((size_t)N * sizeof(float));
    int*   cnt     = (int*)  alloc((size_t)N * sizeof(int));
    int*   ell_row = (int*)  alloc((size_t)N * CAP * sizeof(int));
    float* ell_w   = (float*)alloc((size_t)N * CAP * sizeof(float));
    float* score   = (float*)alloc((size_t)N * sizeof(float));
    float* ebuf    = (float*)alloc((size_t)N * sizeof(float));
    int*   gstart  = (int*)  alloc(GSEG * sizeof(int));
    int*   gend    = (int*)  alloc(GSEG * sizeof(int));
    float* out = (float*)d_out;

    int b = 256;
    int g_init   = (N * NIN + b - 1) / b;
    int g_edges  = (E + b - 1) / b;
    int g_nodes  = (N + b - 1) / b;
    int g_gather = (N * 64 + b - 1) / b;

    k_init<<<g_init, b, 0, stream>>>(agg, deg, cnt, gstart, gend, N);
    k_deg<<<g_edges, b, 0, stream>>>(col, ew, deg, E);
    k_dinv<<<g_nodes, b, 0, stream>>>(deg, N);
    k_fill<<<g_edges, b, 0, stream>>>(row, col, ew, deg, cnt, ell_row, ell_w, agg, x, E);
    k_bounds<<<g_nodes, b, 0, stream>>>(seg, gstart, gend, N);
    k_gather<<<g_gather, b, 0, stream>>>(x, deg, cnt, ell_row, ell_w, agg, Wp, bp, score, N);
    k_softmax<<<GSEG, b, 0, stream>>>(score, gstart, gend, ebuf, out);
    k_pool<<<GSEG * POOL_SPLIT, b, 0, stream>>>(agg, ebuf, We, be, gstart, gend, out);
}

// Round 2
// 269.083 us; speedup vs baseline: 1.1046x; 1.1046x over previous
//
#include <hip/hip_runtime.h>
#include <math.h>

#define NIN 64
#define CAP 16
#define GSEG 250
#define POOL_SPLIT 16

__device__ __forceinline__ float wave_reduce_sum(float v) {
    #pragma unroll
    for (int off = 32; off > 0; off >>= 1) v += __shfl_xor(v, off);
    return v;
}

// init: agg = 0, deg = 1 (self-loop weight), cnt = 0
__global__ void k_init(float* __restrict__ agg, float* __restrict__ deg,
                       int* __restrict__ cnt, int n) {
    int i = blockIdx.x * blockDim.x + threadIdx.x;
    if (i < n * NIN) agg[i] = 0.0f;
    if (i < n) { deg[i] = 1.0f; cnt[i] = 0; }
}

__global__ void k_deg(const int* __restrict__ col, const float* __restrict__ ew,
                      float* __restrict__ deg, int e) {
    int i = blockIdx.x * blockDim.x + threadIdx.x;
    if (i < e) atomicAdd(&deg[col[i]], ew[i]);
}

// fused: deg -> dinv (rsqrt), and segment bounds from sorted segment_ids
__global__ void k_node(float* __restrict__ deg, const int* __restrict__ seg,
                       int* __restrict__ gstart, int* __restrict__ gend, int n) {
    int i = blockIdx.x * blockDim.x + threadIdx.x;
    if (i >= n) return;
    deg[i] = rsqrtf(deg[i]);   // deg >= 1 always
    int s = seg[i];
    if (i == 0 || seg[i - 1] != s) gstart[s] = i;
    if (i == n - 1 || seg[i + 1] != s) gend[s] = i + 1;
}

// Build packed ELL (row, weight) keyed by destination. Overflow edges scatter
// directly into agg (agg already zeroed; gather adds on top).
__global__ void k_fill(const int* __restrict__ row, const int* __restrict__ col,
                       const float* __restrict__ ew, const float* __restrict__ dinv,
                       int* __restrict__ cnt, int2* __restrict__ ell,
                       float* __restrict__ agg, const float* __restrict__ x, int e) {
    int i = blockIdx.x * blockDim.x + threadIdx.x;
    if (i >= e) return;
    int r = row[i], c = col[i];
    float w = dinv[r] * ew[i] * dinv[c];
    int slot = atomicAdd(&cnt[c], 1);
    if (slot < CAP) {
        int2 p; p.x = r; p.y = __float_as_int(w);
        ell[(size_t)c * CAP + slot] = p;
    } else {
        const float* xr = x + (size_t)r * NIN;
        float* ag = agg + (size_t)c * NIN;
        for (int j = 0; j < NIN; ++j) atomicAdd(&ag[j], w * xr[j]);
    }
}

// One wave per node. Fully-unrolled predicated ELL loop -> all x-row loads in a
// half-batch are independent (ILP ~8) instead of a serial dependent chain.
// Fused score GEMV: score[c] = dot(agg_row, W_pool) + b_pool.
__global__ void __launch_bounds__(256)
k_gather(const float* __restrict__ x, const float* __restrict__ dinv,
         const int* __restrict__ cnt, const int2* __restrict__ ell,
         float* __restrict__ agg, const float* __restrict__ Wp,
         const float* __restrict__ bp, float* __restrict__ score, int n) {
    int wave = (int)((blockIdx.x * (size_t)blockDim.x + threadIdx.x) >> 6);
    int lane = threadIdx.x & 63;
    if (wave >= n) return;
    int c = wave;
    float di = dinv[c];
    int m = cnt[c]; if (m > CAP) m = CAP;
    const int2* el = ell + (size_t)c * CAP;

    float a0 = di * di * x[(size_t)c * NIN + lane];
    float a1 = 0.0f, a2 = 0.0f, a3 = 0.0f;

    #pragma unroll
    for (int k = 0; k < 8; ++k) {
        int2 p = el[k];                       // broadcast 8B load (may be garbage)
        bool v = k < m;
        int r = v ? p.x : 0;                  // clamp garbage index -> safe addr
        float w = v ? __int_as_float(p.y) : 0.0f;
        float xv = x[(size_t)r * NIN + lane];
        if ((k & 3) == 0) a0 += w * xv;
        else if ((k & 3) == 1) a1 += w * xv;
        else if ((k & 3) == 2) a2 += w * xv;
        else a3 += w * xv;
    }
    if (m > 8) {
        #pragma unroll
        for (int k = 8; k < CAP; ++k) {
            int2 p = el[k];
            bool v = k < m;
            int r = v ? p.x : 0;
            float w = v ? __int_as_float(p.y) : 0.0f;
            float xv = x[(size_t)r * NIN + lane];
            if ((k & 3) == 0) a0 += w * xv;
            else if ((k & 3) == 1) a1 += w * xv;
            else if ((k & 3) == 2) a2 += w * xv;
            else a3 += w * xv;
        }
    }

    float* ag = agg + (size_t)c * NIN;
    float acc = a0 + a1 + a2 + a3 + ag[lane];   // + overflow contributions
    ag[lane] = acc;
    float vsum = wave_reduce_sum(acc * Wp[lane]);
    if (lane == 0) score[c] = vsum + bp[0];
}

// One block (256 thr) per graph: stable softmax over its node range; also zero out rows.
__global__ void __launch_bounds__(256)
k_softmax(const float* __restrict__ score, const int* __restrict__ gstart,
          const int* __restrict__ gend, float* __restrict__ ebuf,
          float* __restrict__ out) {
    int g = blockIdx.x;
    int s = gstart[g], e = gend[g];
    int tid = threadIdx.x;
    __shared__ float red[4];
    __shared__ float bcast;
    if (tid < NIN) out[(size_t)g * NIN + tid] = 0.0f;

    float mx = -3.402823466e38f;
    for (int i = s + tid; i < e; i += blockDim.x) mx = fmaxf(mx, score[i]);
    #pragma unroll
    for (int off = 32; off > 0; off >>= 1) mx = fmaxf(mx, __shfl_xor(mx, off));
    if ((tid & 63) == 0) red[tid >> 6] = mx;
    __syncthreads();
    if (tid == 0) bcast = fmaxf(fmaxf(red[0], red[1]), fmaxf(red[2], red[3]));
    __syncthreads();
    float m = bcast;

    float sm = 0.0f;
    for (int i = s + tid; i < e; i += blockDim.x) {
        float ev = __expf(score[i] - m);
        ebuf[i] = ev;
        sm += ev;
    }
    sm = wave_reduce_sum(sm);
    __syncthreads();
    if ((tid & 63) == 0) red[tid >> 6] = sm;
    __syncthreads();
    if (tid == 0) bcast = red[0] + red[1] + red[2] + red[3];
    __syncthreads();
    float z = bcast;
    float inv = (z > 0.0f) ? 1.0f / z : 0.0f;
    for (int i = s + tid; i < e; i += blockDim.x) ebuf[i] *= inv;
}

// POOL_SPLIT blocks per graph; wave per node-slice; per-lane W_embed column in VGPRs.
// out[g][j] += sum_n s[n] * relu( dot(agg[n], W_embed[:,j]) + b[j] )
__global__ void __launch_bounds__(256)
k_pool(const float* __restrict__ agg, const float* __restrict__ ebuf,
       const float* __restrict__ We, const float* __restrict__ be,
       const int* __restrict__ gstart, const int* __restrict__ gend,
       float* __restrict__ out) {
    int g = blockIdx.x / POOL_SPLIT;
    int p = blockIdx.x % POOL_SPLIT;
    int tid = threadIdx.x;
    int wv = tid >> 6, lane = tid & 63;

    float wcol[NIN];
    #pragma unroll
    for (int k = 0; k < NIN; ++k) wcol[k] = We[k * NIN + lane];
    float bj = be[lane];

    __shared__ float part[4][NIN];
    int s = gstart[g], e = gend[g];
    float acc = 0.0f;
    for (int n = s + p * 4 + wv; n < e; n += POOL_SPLIT * 4) {
        float a = agg[(size_t)n * NIN + lane];
        float sw = ebuf[n];
        float emb = bj;
        #pragma unroll
        for (int k = 0; k < NIN; ++k) emb += __shfl(a, k) * wcol[k];
        emb = fmaxf(emb, 0.0f);
        acc += sw * emb;
    }
    part[wv][lane] = acc;
    __syncthreads();
    if (wv == 0) {
        float r = part[0][lane] + part[1][lane] + part[2][lane] + part[3][lane];
        atomicAdd(&out[(size_t)g * NIN + lane], r);
    }
}

extern "C" void kernel_launch(void* const* d_in, const int* in_sizes, int n_in,
                              void* d_out, int out_size, void* d_ws, size_t ws_size,
                              hipStream_t stream) {
    const float* x  = (const float*)d_in[0];
    const float* We = (const float*)d_in[1];
    const float* be = (const float*)d_in[2];
    const float* Wp = (const float*)d_in[3];
    const float* bp = (const float*)d_in[4];
    const float* ew = (const float*)d_in[5];
    const int* eidx = (const int*)d_in[6];
    const int* seg  = (const int*)d_in[7];

    int N = in_sizes[0] / NIN;
    int E = in_sizes[5];
    const int* row = eidx;
    const int* col = eidx + E;

    char* w = (char*)d_ws;
    auto alloc = [&](size_t bytes) {
        char* p = w;
        w += (bytes + 255) & ~(size_t)255;
        return p;
    };
    float* agg    = (float*)alloc((size_t)N * NIN * sizeof(float));
    float* deg    = (float*)alloc((size_t)N * sizeof(float));
    int*   cnt    = (int*)  alloc((size_t)N * sizeof(int));
    int2*  ell    = (int2*) alloc((size_t)N * CAP * sizeof(int2));
    float* score  = (float*)alloc((size_t)N * sizeof(float));
    float* ebuf   = (float*)alloc((size_t)N * sizeof(float));
    int*   gstart = (int*)  alloc(GSEG * sizeof(int));
    int*   gend   = (int*)  alloc(GSEG * sizeof(int));
    float* out = (float*)d_out;

    int b = 256;
    int g_init   = (N * NIN + b - 1) / b;
    int g_edges  = (E + b - 1) / b;
    int g_nodes  = (N + b - 1) / b;
    int g_gather = (N * 64 + b - 1) / b;

    k_init<<<g_init, b, 0, stream>>>(agg, deg, cnt, N);
    k_deg<<<g_edges, b, 0, stream>>>(col, ew, deg, E);
    k_node<<<g_nodes, b, 0, stream>>>(deg, seg, gstart, gend, N);
    k_fill<<<g_edges, b, 0, stream>>>(row, col, ew, deg, cnt, ell, agg, x, E);
    k_gather<<<g_gather, b, 0, stream>>>(x, deg, cnt, ell, agg, Wp, bp, score, N);
    k_softmax<<<GSEG, b, 0, stream>>>(score, gstart, gend, ebuf, out);
    k_pool<<<GSEG * POOL_SPLIT, b, 0, stream>>>(agg, ebuf, We, be, gstart, gend, out);
}

// Round 3
// 188.805 us; speedup vs baseline: 1.5742x; 1.4252x over previous
//
#include <hip/hip_runtime.h>
#include <math.h>

#define NIN 64
#define CAP 16
#define GSEG 250
#define POOL_SPLIT 16

__device__ __forceinline__ float wave_reduce_sum(float v) {
    #pragma unroll
    for (int off = 32; off > 0; off >>= 1) v += __shfl_xor(v, off);
    return v;
}

__device__ __forceinline__ unsigned short f2bf(float f) {
    unsigned int u = __float_as_uint(f);
    u += 0x7FFFu + ((u >> 16) & 1u);   // round-to-nearest-even
    return (unsigned short)(u >> 16);
}
__device__ __forceinline__ float bf2f(unsigned short h) {
    return __uint_as_float(((unsigned int)h) << 16);
}

// init: agg(f32 overflow buf) = 0, x16 = bf16(x), deg = 1 (self-loop), cnt = 0
__global__ void k_init(float* __restrict__ agg, unsigned short* __restrict__ x16,
                       const float* __restrict__ x, float* __restrict__ deg,
                       int* __restrict__ cnt, int n) {
    int i = blockIdx.x * blockDim.x + threadIdx.x;
    if (i < n * NIN) { agg[i] = 0.0f; x16[i] = f2bf(x[i]); }
    if (i < n) { deg[i] = 1.0f; cnt[i] = 0; }
}

__global__ void k_deg(const int* __restrict__ col, const float* __restrict__ ew,
                      float* __restrict__ deg, int e) {
    int i = blockIdx.x * blockDim.x + threadIdx.x;
    if (i < e) atomicAdd(&deg[col[i]], ew[i]);
}

// fused: deg -> dinv (rsqrt), and segment bounds from sorted segment_ids
__global__ void k_node(float* __restrict__ deg, const int* __restrict__ seg,
                       int* __restrict__ gstart, int* __restrict__ gend, int n) {
    int i = blockIdx.x * blockDim.x + threadIdx.x;
    if (i >= n) return;
    deg[i] = rsqrtf(deg[i]);   // deg >= 1 always
    int s = seg[i];
    if (i == 0 || seg[i - 1] != s) gstart[s] = i;
    if (i == n - 1 || seg[i + 1] != s) gend[s] = i + 1;
}

// Build packed ELL (row, weight) keyed by destination. Overflow edges scatter
// directly into f32 agg (zeroed; gather adds on top only when cnt>CAP).
__global__ void k_fill(const int* __restrict__ row, const int* __restrict__ col,
                       const float* __restrict__ ew, const float* __restrict__ dinv,
                       int* __restrict__ cnt, int2* __restrict__ ell,
                       float* __restrict__ agg, const float* __restrict__ x, int e) {
    int i = blockIdx.x * blockDim.x + threadIdx.x;
    if (i >= e) return;
    int r = row[i], c = col[i];
    float w = dinv[r] * ew[i] * dinv[c];
    int slot = atomicAdd(&cnt[c], 1);
    if (slot < CAP) {
        int2 p; p.x = r; p.y = __float_as_int(w);
        ell[(size_t)c * CAP + slot] = p;
    } else {
        const float* xr = x + (size_t)r * NIN;
        float* ag = agg + (size_t)c * NIN;
        for (int j = 0; j < NIN; ++j) atomicAdd(&ag[j], w * xr[j]);
    }
}

// Two nodes per wave; bf16 x gather; fully-unrolled predicated ELL batches.
// Writes agg16 (bf16). Fused score GEMV.
__global__ void __launch_bounds__(256)
k_gather(const unsigned short* __restrict__ x16, const float* __restrict__ dinv,
         const int* __restrict__ cnt, const int2* __restrict__ ell,
         const float* __restrict__ aggf, unsigned short* __restrict__ agg16,
         const float* __restrict__ Wp, const float* __restrict__ bp,
         float* __restrict__ score, int n) {
    int wid = (int)((blockIdx.x * (size_t)blockDim.x + threadIdx.x) >> 6);
    int lane = threadIdx.x & 63;
    int c0 = wid * 2, c1 = wid * 2 + 1;
    if (c0 >= n) return;
    bool has1 = c1 < n;
    int c1g = has1 ? c1 : c0;

    float di0 = dinv[c0], di1 = dinv[c1g];
    int cr0 = cnt[c0], cr1 = cnt[c1g];
    int m0 = cr0 < CAP ? cr0 : CAP;
    int m1 = has1 ? (cr1 < CAP ? cr1 : CAP) : 0;
    const int2* e0p = ell + (size_t)c0 * CAP;
    const int2* e1p = ell + (size_t)c1g * CAP;

    float acc0 = di0 * di0 * bf2f(x16[(size_t)c0 * NIN + lane]);
    float acc1 = has1 ? di1 * di1 * bf2f(x16[(size_t)c1g * NIN + lane]) : 0.0f;
    float b0 = 0.0f, b1 = 0.0f;

    #pragma unroll
    for (int k = 0; k < 8; ++k) {
        int2 p0 = e0p[k]; int2 p1 = e1p[k];
        bool v0 = k < m0, v1 = k < m1;
        int r0 = v0 ? p0.x : 0; float w0 = v0 ? __int_as_float(p0.y) : 0.0f;
        int r1 = v1 ? p1.x : 0; float w1 = v1 ? __int_as_float(p1.y) : 0.0f;
        float xv0 = bf2f(x16[(size_t)r0 * NIN + lane]);
        float xv1 = bf2f(x16[(size_t)r1 * NIN + lane]);
        if (k & 1) { b0 += w0 * xv0; b1 += w1 * xv1; }
        else       { acc0 += w0 * xv0; acc1 += w1 * xv1; }
    }
    if (m0 > 8 || m1 > 8) {
        #pragma unroll
        for (int k = 8; k < CAP; ++k) {
            int2 p0 = e0p[k]; int2 p1 = e1p[k];
            bool v0 = k < m0, v1 = k < m1;
            int r0 = v0 ? p0.x : 0; float w0 = v0 ? __int_as_float(p0.y) : 0.0f;
            int r1 = v1 ? p1.x : 0; float w1 = v1 ? __int_as_float(p1.y) : 0.0f;
            float xv0 = bf2f(x16[(size_t)r0 * NIN + lane]);
            float xv1 = bf2f(x16[(size_t)r1 * NIN + lane]);
            if (k & 1) { b0 += w0 * xv0; b1 += w1 * xv1; }
            else       { acc0 += w0 * xv0; acc1 += w1 * xv1; }
        }
    }
    acc0 += b0; acc1 += b1;
    if (cr0 > CAP)          acc0 += aggf[(size_t)c0 * NIN + lane];
    if (has1 && cr1 > CAP)  acc1 += aggf[(size_t)c1 * NIN + lane];

    agg16[(size_t)c0 * NIN + lane] = f2bf(acc0);
    if (has1) agg16[(size_t)c1 * NIN + lane] = f2bf(acc1);

    float wp = Wp[lane];
    float s0 = wave_reduce_sum(acc0 * wp);
    float s1 = wave_reduce_sum(acc1 * wp);
    if (lane == 0) {
        float bb = bp[0];
        score[c0] = s0 + bb;
        if (has1) score[c1] = s1 + bb;
    }
}

// One block (256 thr) per graph: stable softmax over its node range; also zero out rows.
__global__ void __launch_bounds__(256)
k_softmax(const float* __restrict__ score, const int* __restrict__ gstart,
          const int* __restrict__ gend, float* __restrict__ ebuf,
          float* __restrict__ out) {
    int g = blockIdx.x;
    int s = gstart[g], e = gend[g];
    int tid = threadIdx.x;
    __shared__ float red[4];
    __shared__ float bcast;
    if (tid < NIN) out[(size_t)g * NIN + tid] = 0.0f;

    float mx = -3.402823466e38f;
    for (int i = s + tid; i < e; i += blockDim.x) mx = fmaxf(mx, score[i]);
    #pragma unroll
    for (int off = 32; off > 0; off >>= 1) mx = fmaxf(mx, __shfl_xor(mx, off));
    if ((tid & 63) == 0) red[tid >> 6] = mx;
    __syncthreads();
    if (tid == 0) bcast = fmaxf(fmaxf(red[0], red[1]), fmaxf(red[2], red[3]));
    __syncthreads();
    float m = bcast;

    float sm = 0.0f;
    for (int i = s + tid; i < e; i += blockDim.x) {
        float ev = __expf(score[i] - m);
        ebuf[i] = ev;
        sm += ev;
    }
    sm = wave_reduce_sum(sm);
    __syncthreads();
    if ((tid & 63) == 0) red[tid >> 6] = sm;
    __syncthreads();
    if (tid == 0) bcast = red[0] + red[1] + red[2] + red[3];
    __syncthreads();
    float z = bcast;
    float inv = (z > 0.0f) ? 1.0f / z : 0.0f;
    for (int i = s + tid; i < e; i += blockDim.x) ebuf[i] *= inv;
}

// POOL_SPLIT blocks per graph. Per-lane W column held in 16 NAMED float4s
// (guaranteed registers). Node agg row staged via LDS, read back as broadcast
// ds_read_b128. 4 independent FMA chains. Next-node prefetch.
#define WLOAD(i) float4 wq##i = make_float4(We[(4*(i)+0)*NIN+lane], We[(4*(i)+1)*NIN+lane], \
                                            We[(4*(i)+2)*NIN+lane], We[(4*(i)+3)*NIN+lane]);
#define WSTEP(i) { float4 av = *(const float4*)&als[wv][4*(i)]; \
    e0 = fmaf(av.x, wq##i.x, e0); e1 = fmaf(av.y, wq##i.y, e1); \
    e2 = fmaf(av.z, wq##i.z, e2); e3 = fmaf(av.w, wq##i.w, e3); }

__global__ void __launch_bounds__(256)
k_pool(const unsigned short* __restrict__ agg16, const float* __restrict__ ebuf,
       const float* __restrict__ We, const float* __restrict__ be,
       const int* __restrict__ gstart, const int* __restrict__ gend,
       float* __restrict__ out) {
    int g = blockIdx.x / POOL_SPLIT;
    int p = blockIdx.x % POOL_SPLIT;
    int tid = threadIdx.x;
    int wv = tid >> 6, lane = tid & 63;

    WLOAD(0) WLOAD(1) WLOAD(2) WLOAD(3) WLOAD(4) WLOAD(5) WLOAD(6) WLOAD(7)
    WLOAD(8) WLOAD(9) WLOAD(10) WLOAD(11) WLOAD(12) WLOAD(13) WLOAD(14) WLOAD(15)
    float bj = be[lane];

    __shared__ float als[4][NIN];
    __shared__ float part[4][NIN];

    int s = gstart[g], e = gend[g];
    const int stride = POOL_SPLIT * 4;
    int n = s + p * 4 + wv;
    float acc = 0.0f;

    float a_cur = 0.0f, sw_cur = 0.0f;
    if (n < e) {
        a_cur = bf2f(agg16[(size_t)n * NIN + lane]);
        sw_cur = ebuf[n];
    }
    while (n < e) {
        int nn = n + stride;
        bool vn = nn < e;
        int ni = vn ? nn : n;
        float a_nxt = bf2f(agg16[(size_t)ni * NIN + lane]);   // prefetch
        float sw_nxt = ebuf[ni];

        als[wv][lane] = a_cur;
        float e0 = bj, e1 = 0.0f, e2 = 0.0f, e3 = 0.0f;
        WSTEP(0) WSTEP(1) WSTEP(2) WSTEP(3) WSTEP(4) WSTEP(5) WSTEP(6) WSTEP(7)
        WSTEP(8) WSTEP(9) WSTEP(10) WSTEP(11) WSTEP(12) WSTEP(13) WSTEP(14) WSTEP(15)
        float emb = fmaxf(e0 + e1 + e2 + e3, 0.0f);
        acc = fmaf(sw_cur, emb, acc);

        a_cur = a_nxt; sw_cur = sw_nxt;
        n = nn;
    }
    part[wv][lane] = acc;
    __syncthreads();
    if (wv == 0) {
        float r = part[0][lane] + part[1][lane] + part[2][lane] + part[3][lane];
        atomicAdd(&out[(size_t)g * NIN + lane], r);
    }
}

extern "C" void kernel_launch(void* const* d_in, const int* in_sizes, int n_in,
                              void* d_out, int out_size, void* d_ws, size_t ws_size,
                              hipStream_t stream) {
    const float* x  = (const float*)d_in[0];
    const float* We = (const float*)d_in[1];
    const float* be = (const float*)d_in[2];
    const float* Wp = (const float*)d_in[3];
    const float* bp = (const float*)d_in[4];
    const float* ew = (const float*)d_in[5];
    const int* eidx = (const int*)d_in[6];
    const int* seg  = (const int*)d_in[7];

    int N = in_sizes[0] / NIN;
    int E = in_sizes[5];
    const int* row = eidx;
    const int* col = eidx + E;

    char* w = (char*)d_ws;
    auto alloc = [&](size_t bytes) {
        char* p = w;
        w += (bytes + 255) & ~(size_t)255;
        return p;
    };
    float*          aggf  = (float*)alloc((size_t)N * NIN * sizeof(float));
    unsigned short* x16   = (unsigned short*)alloc((size_t)N * NIN * sizeof(short));
    unsigned short* agg16 = (unsigned short*)alloc((size_t)N * NIN * sizeof(short));
    float* deg    = (float*)alloc((size_t)N * sizeof(float));
    int*   cnt    = (int*)  alloc((size_t)N * sizeof(int));
    int2*  ell    = (int2*) alloc((size_t)N * CAP * sizeof(int2));
    float* score  = (float*)alloc((size_t)N * sizeof(float));
    float* ebuf   = (float*)alloc((size_t)N * sizeof(float));
    int*   gstart = (int*)  alloc(GSEG * sizeof(int));
    int*   gend   = (int*)  alloc(GSEG * sizeof(int));
    float* out = (float*)d_out;

    int b = 256;
    int g_init   = (N * NIN + b - 1) / b;
    int g_edges  = (E + b - 1) / b;
    int g_nodes  = (N + b - 1) / b;
    int nwaves   = (N + 1) / 2;
    int g_gather = (nwaves + 3) / 4;

    k_init<<<g_init, b, 0, stream>>>(aggf, x16, x, deg, cnt, N);
    k_deg<<<g_edges, b, 0, stream>>>(col, ew, deg, E);
    k_node<<<g_nodes, b, 0, stream>>>(deg, seg, gstart, gend, N);
    k_fill<<<g_edges, b, 0, stream>>>(row, col, ew, deg, cnt, ell, aggf, x, E);
    k_gather<<<g_gather, b, 0, stream>>>(x16, deg, cnt, ell, aggf, agg16, Wp, bp, score, N);
    k_softmax<<<GSEG, b, 0, stream>>>(score, gstart, gend, ebuf, out);
    k_pool<<<GSEG * POOL_SPLIT, b, 0, stream>>>(agg16, ebuf, We, be, gstart, gend, out);
}

// Round 4
// 151.717 us; speedup vs baseline: 1.9591x; 1.2445x over previous
//
#include <hip/hip_runtime.h>
#include <math.h>

#define NIN 64
#define CAP 16
#define GSEG 250
#define POOL_SPLIT 16

__device__ __forceinline__ float wave_reduce_sum(float v) {
    #pragma unroll
    for (int off = 32; off > 0; off >>= 1) v += __shfl_xor(v, off);
    return v;
}

__device__ __forceinline__ unsigned short f2bf(float f) {
    unsigned int u = __float_as_uint(f);
    u += 0x7FFFu + ((u >> 16) & 1u);   // round-to-nearest-even
    return (unsigned short)(u >> 16);
}
__device__ __forceinline__ float bf2f(unsigned short h) {
    return __uint_as_float(((unsigned int)h) << 16);
}

// init: aggf = 0, x16 = bf16(x), deg = 1 (self-loop), cnt = 0, out = 0, bounds = 0
__global__ void k_init(float4* __restrict__ aggf4, ushort4* __restrict__ x164,
                       const float4* __restrict__ x4, float* __restrict__ deg,
                       int* __restrict__ cnt, float* __restrict__ out,
                       int* __restrict__ gstart, int* __restrict__ gend, int n) {
    int i = blockIdx.x * blockDim.x + threadIdx.x;
    int tot = n * (NIN / 4);
    if (i < tot) {
        float4 v = x4[i];
        ushort4 h;
        h.x = f2bf(v.x); h.y = f2bf(v.y); h.z = f2bf(v.z); h.w = f2bf(v.w);
        x164[i] = h;
        aggf4[i] = make_float4(0.f, 0.f, 0.f, 0.f);
    }
    if (i < n) { deg[i] = 1.0f; cnt[i] = 0; }
    if (i < GSEG * NIN) out[i] = 0.0f;
    if (i < GSEG) { gstart[i] = 0; gend[i] = 0; }
}

__global__ void k_deg(const int* __restrict__ col, const float* __restrict__ ew,
                      float* __restrict__ deg, int e) {
    int i = blockIdx.x * blockDim.x + threadIdx.x;
    if (i < e) atomicAdd(&deg[col[i]], ew[i]);
}

// fused: deg -> dinv (rsqrt), and segment bounds from sorted segment_ids
__global__ void k_node(float* __restrict__ deg, const int* __restrict__ seg,
                       int* __restrict__ gstart, int* __restrict__ gend, int n) {
    int i = blockIdx.x * blockDim.x + threadIdx.x;
    if (i >= n) return;
    deg[i] = rsqrtf(deg[i]);   // deg >= 1 always
    int s = seg[i];
    if (i == 0 || seg[i - 1] != s) gstart[s] = i;
    if (i == n - 1 || seg[i + 1] != s) gend[s] = i + 1;
}

// Build packed ELL (row, weight) keyed by destination. Overflow edges scatter
// directly into f32 aggf (zeroed; gather adds on top only when cnt>CAP).
__global__ void k_fill(const int* __restrict__ row, const int* __restrict__ col,
                       const float* __restrict__ ew, const float* __restrict__ dinv,
                       int* __restrict__ cnt, int2* __restrict__ ell,
                       float* __restrict__ agg, const float* __restrict__ x, int e) {
    int i = blockIdx.x * blockDim.x + threadIdx.x;
    if (i >= e) return;
    int r = row[i], c = col[i];
    float w = dinv[r] * ew[i] * dinv[c];
    int slot = atomicAdd(&cnt[c], 1);
    if (slot < CAP) {
        int2 p; p.x = r; p.y = __float_as_int(w);
        ell[(size_t)c * CAP + slot] = p;
    } else {
        const float* xr = x + (size_t)r * NIN;
        float* ag = agg + (size_t)c * NIN;
        for (int j = 0; j < NIN; ++j) atomicAdd(&ag[j], w * xr[j]);
    }
}

// Quarter-wave gather: 4 nodes per wave, 16 lanes per node, ushort4 per lane.
// One VMEM instruction fetches a slot's source rows for all 4 nodes.
// ELL metadata: one contiguous 512B wave load, distributed via shuffles.
// Fused score GEMV with quarter-wave reduce.
__global__ void __launch_bounds__(256)
k_gather(const ushort* __restrict__ x16, const float* __restrict__ dinv,
         const int* __restrict__ cnt, const int2* __restrict__ ell,
         const float* __restrict__ aggf, ushort* __restrict__ agg16,
         const float* __restrict__ Wp, const float* __restrict__ bp,
         float* __restrict__ score, int n) {
    int wid = (int)((blockIdx.x * (size_t)blockDim.x + threadIdx.x) >> 6);
    int lane = threadIdx.x & 63;
    int q = lane >> 4, l = lane & 15;
    int c0 = wid * 4;
    if (c0 >= n) return;
    int c = c0 + q;
    bool valid = c < n;
    int cc = valid ? c : (n - 1);

    int cr = cnt[cc];
    int m = valid ? (cr < CAP ? cr : CAP) : 0;
    float di = dinv[cc];

    // own node's full ELL row: lane l holds slot l (contiguous 512B wave load)
    int2 pe = ell[(size_t)cc * CAP + l];

    const ushort4* xv4 = (const ushort4*)x16;
    ushort4 xs = xv4[(size_t)cc * 16 + l];
    float s2 = di * di;
    float a0 = s2 * bf2f(xs.x), a1 = s2 * bf2f(xs.y);
    float a2 = s2 * bf2f(xs.z), a3 = s2 * bf2f(xs.w);

    int base = lane & 48;   // first lane of this quarter
    #pragma unroll
    for (int k = 0; k < 8; ++k) {
        int rk = __shfl(pe.x, base + k);
        float wk = __shfl(__int_as_float(pe.y), base + k);
        bool v = k < m;
        int r = v ? rk : 0;
        float w = v ? wk : 0.0f;
        ushort4 xr = xv4[(size_t)r * 16 + l];
        a0 = fmaf(w, bf2f(xr.x), a0);
        a1 = fmaf(w, bf2f(xr.y), a1);
        a2 = fmaf(w, bf2f(xr.z), a2);
        a3 = fmaf(w, bf2f(xr.w), a3);
    }
    if (__any(m > 8)) {
        #pragma unroll
        for (int k = 8; k < CAP; ++k) {
            int rk = __shfl(pe.x, base + k);
            float wk = __shfl(__int_as_float(pe.y), base + k);
            bool v = k < m;
            int r = v ? rk : 0;
            float w = v ? wk : 0.0f;
            ushort4 xr = xv4[(size_t)r * 16 + l];
            a0 = fmaf(w, bf2f(xr.x), a0);
            a1 = fmaf(w, bf2f(xr.y), a1);
            a2 = fmaf(w, bf2f(xr.z), a2);
            a3 = fmaf(w, bf2f(xr.w), a3);
        }
    }
    if (valid && cr > CAP) {
        const float4* af4 = (const float4*)aggf;
        float4 fo = af4[(size_t)cc * 16 + l];
        a0 += fo.x; a1 += fo.y; a2 += fo.z; a3 += fo.w;
    }

    if (valid) {
        ushort4 ho;
        ho.x = f2bf(a0); ho.y = f2bf(a1); ho.z = f2bf(a2); ho.w = f2bf(a3);
        ((ushort4*)agg16)[(size_t)cc * 16 + l] = ho;
    }

    const float4* wp4 = (const float4*)Wp;
    float4 wv = wp4[l];
    float part = a0 * wv.x + a1 * wv.y + a2 * wv.z + a3 * wv.w;
    part += __shfl_xor(part, 1);
    part += __shfl_xor(part, 2);
    part += __shfl_xor(part, 4);
    part += __shfl_xor(part, 8);
    if (l == 0 && valid) score[c] = part + bp[0];
}

// POOL_SPLIT blocks per graph. Fused per-graph softmax (each block recomputes
// m,z over the graph's scores — L2-resident). Per-lane W column in 16 NAMED
// float4s; node agg row staged via LDS broadcast; 4 FMA chains; prefetch.
#define WLOAD(i) float4 wq##i = make_float4(We[(4*(i)+0)*NIN+lane], We[(4*(i)+1)*NIN+lane], \
                                            We[(4*(i)+2)*NIN+lane], We[(4*(i)+3)*NIN+lane]);
#define WSTEP(i) { float4 av = *(const float4*)&als[wv][4*(i)]; \
    e0 = fmaf(av.x, wq##i.x, e0); e1 = fmaf(av.y, wq##i.y, e1); \
    e2 = fmaf(av.z, wq##i.z, e2); e3 = fmaf(av.w, wq##i.w, e3); }

__global__ void __launch_bounds__(256)
k_pool(const ushort* __restrict__ agg16, const float* __restrict__ score,
       const float* __restrict__ We, const float* __restrict__ be,
       const int* __restrict__ gstart, const int* __restrict__ gend,
       float* __restrict__ out) {
    int g = blockIdx.x / POOL_SPLIT;
    int p = blockIdx.x % POOL_SPLIT;
    int tid = threadIdx.x;
    int wv = tid >> 6, lane = tid & 63;
    int s = gstart[g], e = gend[g];

    __shared__ float red[4];
    __shared__ float bc;

    // per-graph max
    float mx = -3.402823466e38f;
    for (int i = s + tid; i < e; i += 256) mx = fmaxf(mx, score[i]);
    #pragma unroll
    for (int off = 32; off > 0; off >>= 1) mx = fmaxf(mx, __shfl_xor(mx, off));
    if (lane == 0) red[wv] = mx;
    __syncthreads();
    if (tid == 0) bc = fmaxf(fmaxf(red[0], red[1]), fmaxf(red[2], red[3]));
    __syncthreads();
    float m = bc;
    __syncthreads();

    // per-graph sum of exp
    float sm = 0.0f;
    for (int i = s + tid; i < e; i += 256) sm += __expf(score[i] - m);
    sm = wave_reduce_sum(sm);
    if (lane == 0) red[wv] = sm;
    __syncthreads();
    if (tid == 0) bc = red[0] + red[1] + red[2] + red[3];
    __syncthreads();
    float invz = (bc > 0.0f) ? 1.0f / bc : 0.0f;

    WLOAD(0) WLOAD(1) WLOAD(2) WLOAD(3) WLOAD(4) WLOAD(5) WLOAD(6) WLOAD(7)
    WLOAD(8) WLOAD(9) WLOAD(10) WLOAD(11) WLOAD(12) WLOAD(13) WLOAD(14) WLOAD(15)
    float bj = be[lane];

    __shared__ float als[4][NIN];
    __shared__ float part[4][NIN];

    const int stride = POOL_SPLIT * 4;
    int n = s + p * 4 + wv;
    float acc = 0.0f;

    float a_cur = 0.0f, sw_cur = 0.0f;
    if (n < e) {
        a_cur = bf2f(agg16[(size_t)n * NIN + lane]);
        sw_cur = __expf(score[n] - m) * invz;
    }
    while (n < e) {
        int nn = n + stride;
        bool vn = nn < e;
        int ni = vn ? nn : n;
        float a_nxt = bf2f(agg16[(size_t)ni * NIN + lane]);   // prefetch
        float sw_nxt = __expf(score[ni] - m) * invz;

        als[wv][lane] = a_cur;
        float e0 = bj, e1 = 0.0f, e2 = 0.0f, e3 = 0.0f;
        WSTEP(0) WSTEP(1) WSTEP(2) WSTEP(3) WSTEP(4) WSTEP(5) WSTEP(6) WSTEP(7)
        WSTEP(8) WSTEP(9) WSTEP(10) WSTEP(11) WSTEP(12) WSTEP(13) WSTEP(14) WSTEP(15)
        float emb = fmaxf(e0 + e1 + e2 + e3, 0.0f);
        acc = fmaf(sw_cur, emb, acc);

        a_cur = a_nxt; sw_cur = sw_nxt;
        n = nn;
    }
    part[wv][lane] = acc;
    __syncthreads();
    if (wv == 0) {
        float r = part[0][lane] + part[1][lane] + part[2][lane] + part[3][lane];
        atomicAdd(&out[(size_t)g * NIN + lane], r);
    }
}

extern "C" void kernel_launch(void* const* d_in, const int* in_sizes, int n_in,
                              void* d_out, int out_size, void* d_ws, size_t ws_size,
                              hipStream_t stream) {
    const float* x  = (const float*)d_in[0];
    const float* We = (const float*)d_in[1];
    const float* be = (const float*)d_in[2];
    const float* Wp = (const float*)d_in[3];
    const float* bp = (const float*)d_in[4];
    const float* ew = (const float*)d_in[5];
    const int* eidx = (const int*)d_in[6];
    const int* seg  = (const int*)d_in[7];

    int N = in_sizes[0] / NIN;
    int E = in_sizes[5];
    const int* row = eidx;
    const int* col = eidx + E;

    char* w = (char*)d_ws;
    auto alloc = [&](size_t bytes) {
        char* p = w;
        w += (bytes + 255) & ~(size_t)255;
        return p;
    };
    float*          aggf  = (float*)alloc((size_t)N * NIN * sizeof(float));
    unsigned short* x16   = (unsigned short*)alloc((size_t)N * NIN * sizeof(short));
    unsigned short* agg16 = (unsigned short*)alloc((size_t)N * NIN * sizeof(short));
    float* deg    = (float*)alloc((size_t)N * sizeof(float));
    int*   cnt    = (int*)  alloc((size_t)N * sizeof(int));
    int2*  ell    = (int2*) alloc((size_t)N * CAP * sizeof(int2));
    float* score  = (float*)alloc((size_t)N * sizeof(float));
    int*   gstart = (int*)  alloc(GSEG * sizeof(int));
    int*   gend   = (int*)  alloc(GSEG * sizeof(int));
    float* out = (float*)d_out;

    int b = 256;
    int g_init   = (N * (NIN / 4) + b - 1) / b;
    int g_edges  = (E + b - 1) / b;
    int g_nodes  = (N + b - 1) / b;
    int nwaves   = (N + 3) / 4;
    int g_gather = (nwaves + 3) / 4;

    k_init<<<g_init, b, 0, stream>>>((float4*)aggf, (ushort4*)x16, (const float4*)x,
                                     deg, cnt, out, gstart, gend, N);
    k_deg<<<g_edges, b, 0, stream>>>(col, ew, deg, E);
    k_node<<<g_nodes, b, 0, stream>>>(deg, seg, gstart, gend, N);
    k_fill<<<g_edges, b, 0, stream>>>(row, col, ew, deg, cnt, ell, aggf, x, E);
    k_gather<<<g_gather, b, 0, stream>>>(x16, deg, cnt, ell, aggf, agg16, Wp, bp, score, N);
    k_pool<<<GSEG * POOL_SPLIT, b, 0, stream>>>(agg16, score, We, be, gstart, gend, out);
}

// Round 5
// 143.208 us; speedup vs baseline: 2.0755x; 1.0594x over previous
//
#include <hip/hip_runtime.h>
#include <math.h>

#define NIN 64
#define CAP 16
#define GSEG 250
#define POOL_SPLIT 16

__device__ __forceinline__ float wave_reduce_sum(float v) {
    #pragma unroll
    for (int off = 32; off > 0; off >>= 1) v += __shfl_xor(v, off);
    return v;
}

__device__ __forceinline__ unsigned short f2bf(float f) {
    unsigned int u = __float_as_uint(f);
    u += 0x7FFFu + ((u >> 16) & 1u);   // round-to-nearest-even
    return (unsigned short)(u >> 16);
}
__device__ __forceinline__ float bf2f(unsigned short h) {
    return __uint_as_float(((unsigned int)h) << 16);
}

// 15-bit float for w in (0,1]: 5-bit exp (bias so exp8=97..127 -> 1..31), 10-bit mantissa.
__device__ __forceinline__ unsigned int f15enc(float w) {
    unsigned int u = __float_as_uint(w);           // w >= 0
    u += 0x0FFFu + ((u >> 13) & 1u);               // RNE to 10-bit mantissa
    int e5 = (int)(u >> 23) - 96;
    if (e5 <= 0) return 0u;                        // underflow -> 0
    unsigned int m = (u >> 13) & 0x3FFu;
    if (e5 > 31) { e5 = 31; m = 0x3FFu; }
    return ((unsigned int)e5 << 10) | m;
}
__device__ __forceinline__ float f15dec(unsigned int f) {
    if (f == 0u) return 0.0f;
    return __uint_as_float((((f >> 10) + 96u) << 23) | ((f & 0x3FFu) << 13));
}

// init: aggf = 0, x16 = bf16(x), deg = 1 (self-loop), cnt = 0, out = 0, bounds = 0, ovf_cnt = 0
__global__ void k_init(float4* __restrict__ aggf4, ushort4* __restrict__ x164,
                       const float4* __restrict__ x4, float* __restrict__ deg,
                       int* __restrict__ cnt, float* __restrict__ out,
                       int* __restrict__ gstart, int* __restrict__ gend,
                       int* __restrict__ ovf_cnt, int n) {
    int i = blockIdx.x * blockDim.x + threadIdx.x;
    int tot = n * (NIN / 4);
    if (i < tot) {
        float4 v = x4[i];
        ushort4 h;
        h.x = f2bf(v.x); h.y = f2bf(v.y); h.z = f2bf(v.z); h.w = f2bf(v.w);
        x164[i] = h;
        aggf4[i] = make_float4(0.f, 0.f, 0.f, 0.f);
    }
    if (i < n) { deg[i] = 1.0f; cnt[i] = 0; }
    if (i < GSEG * NIN) out[i] = 0.0f;
    if (i < GSEG) { gstart[i] = 0; gend[i] = 0; }
    if (i == 0) *ovf_cnt = 0;
}

// XCD-sharded fill (fused deg accumulation). Each chunk of 256 edges is visited
// by 8 blocks; block handles only edges with (col & 7) == (blockIdx & 7).
// With round-robin block->XCD dispatch, each node's 64B ELL line is written by
// exactly one XCD -> assembles in its L2, evicted once (kills 4x write amp).
__global__ void __launch_bounds__(256)
k_fill(const int* __restrict__ row, const int* __restrict__ col,
       const float* __restrict__ ew, float* __restrict__ deg,
       int* __restrict__ cnt, unsigned int* __restrict__ ell,
       int2* __restrict__ ovf, int* __restrict__ ovf_cnt, int e) {
    int xshard = blockIdx.x & 7;
    int i = (blockIdx.x >> 3) * 256 + threadIdx.x;
    if (i >= e) return;
    int c = col[i];
    if ((c & 7) != xshard) return;
    int r = row[i];
    float w = ew[i];
    atomicAdd(&deg[c], w);
    unsigned int p = ((unsigned int)r << 15) | f15enc(w);
    int slot = atomicAdd(&cnt[c], 1);
    if (slot < CAP) {
        ell[(size_t)c * CAP + slot] = p;
    } else {
        int oi = atomicAdd(ovf_cnt, 1);
        ovf[oi] = make_int2(c, (int)p);
    }
}

// fused: deg -> dinv (rsqrt), and segment bounds from sorted segment_ids
__global__ void k_node(float* __restrict__ deg, const int* __restrict__ seg,
                       int* __restrict__ gstart, int* __restrict__ gend, int n) {
    int i = blockIdx.x * blockDim.x + threadIdx.x;
    if (i >= n) return;
    deg[i] = rsqrtf(deg[i]);   // deg >= 1 always
    int s = seg[i];
    if (i == 0 || seg[i - 1] != s) gstart[s] = i;
    if (i == n - 1 || seg[i + 1] != s) gend[s] = i + 1;
}

// Replay overflow edges (slot >= CAP, ~hundreds) into f32 aggf. One wave per entry.
__global__ void k_ovf(const int2* __restrict__ ovf, const int* __restrict__ ovf_cnt,
                      const float* __restrict__ dinv, const ushort* __restrict__ x16,
                      float* __restrict__ aggf) {
    int nov = *ovf_cnt;
    int wid = (int)((blockIdx.x * (size_t)blockDim.x + threadIdx.x) >> 6);
    int lane = threadIdx.x & 63;
    int nw = (int)((gridDim.x * (size_t)blockDim.x) >> 6);
    for (int i = wid; i < nov; i += nw) {
        int2 ov = ovf[i];
        int c = ov.x;
        unsigned int p = (unsigned int)ov.y;
        int r = (int)(p >> 15);
        float w = f15dec(p & 0x7FFFu) * dinv[r] * dinv[c];
        atomicAdd(&aggf[(size_t)c * NIN + lane], w * bf2f(x16[(size_t)r * NIN + lane]));
    }
}

// Quarter-wave gather: 4 nodes/wave, 16 lanes/node, ushort4 per lane.
// ELL row per node = one 64B line of packed 4B entries; per-lane w' = dinv[r]*ew
// premultiplied, distributed to slots via shuffles. total = di*(di*x_self + sum w' x_r).
__global__ void __launch_bounds__(256)
k_gather(const ushort* __restrict__ x16, const float* __restrict__ dinv,
         const int* __restrict__ cnt, const unsigned int* __restrict__ ell,
         const float* __restrict__ aggf, ushort* __restrict__ agg16,
         const float* __restrict__ Wp, const float* __restrict__ bp,
         float* __restrict__ score, int n) {
    int wid = (int)((blockIdx.x * (size_t)blockDim.x + threadIdx.x) >> 6);
    int lane = threadIdx.x & 63;
    int q = lane >> 4, l = lane & 15;
    int c0 = wid * 4;
    if (c0 >= n) return;
    int c = c0 + q;
    bool valid = c < n;
    int cc = valid ? c : (n - 1);

    int cr = cnt[cc];
    int m = valid ? (cr < CAP ? cr : CAP) : 0;
    float di = dinv[cc];

    // lane l holds slot l of its node's ELL row (wave: 4 nodes x 64B contiguous)
    unsigned int pe = ell[(size_t)cc * CAP + l];
    int pr = (int)(pe >> 15);
    float pw = f15dec(pe & 0x7FFFu) * dinv[pr];   // w' = dinv[r]*ew (garbage ok, predicated)

    const ushort4* xv4 = (const ushort4*)x16;
    ushort4 xs = xv4[(size_t)cc * 16 + l];
    float a0 = di * bf2f(xs.x), a1 = di * bf2f(xs.y);
    float a2 = di * bf2f(xs.z), a3 = di * bf2f(xs.w);

    int base = lane & 48;   // first lane of this quarter
    #pragma unroll
    for (int k = 0; k < 8; ++k) {
        int rk = __shfl(pr, base + k);
        float wk = __shfl(pw, base + k);
        bool v = k < m;
        int r = v ? rk : 0;
        float w = v ? wk : 0.0f;
        ushort4 xr = xv4[(size_t)r * 16 + l];
        a0 = fmaf(w, bf2f(xr.x), a0);
        a1 = fmaf(w, bf2f(xr.y), a1);
        a2 = fmaf(w, bf2f(xr.z), a2);
        a3 = fmaf(w, bf2f(xr.w), a3);
    }
    if (__any(m > 8)) {
        #pragma unroll
        for (int k = 8; k < CAP; ++k) {
            int rk = __shfl(pr, base + k);
            float wk = __shfl(pw, base + k);
            bool v = k < m;
            int r = v ? rk : 0;
            float w = v ? wk : 0.0f;
            ushort4 xr = xv4[(size_t)r * 16 + l];
            a0 = fmaf(w, bf2f(xr.x), a0);
            a1 = fmaf(w, bf2f(xr.y), a1);
            a2 = fmaf(w, bf2f(xr.z), a2);
            a3 = fmaf(w, bf2f(xr.w), a3);
        }
    }
    a0 *= di; a1 *= di; a2 *= di; a3 *= di;

    if (valid && cr > CAP) {
        const float4* af4 = (const float4*)aggf;
        float4 fo = af4[(size_t)cc * 16 + l];
        a0 += fo.x; a1 += fo.y; a2 += fo.z; a3 += fo.w;
    }

    if (valid) {
        ushort4 ho;
        ho.x = f2bf(a0); ho.y = f2bf(a1); ho.z = f2bf(a2); ho.w = f2bf(a3);
        ((ushort4*)agg16)[(size_t)cc * 16 + l] = ho;
    }

    const float4* wp4 = (const float4*)Wp;
    float4 wv = wp4[l];
    float part = a0 * wv.x + a1 * wv.y + a2 * wv.z + a3 * wv.w;
    part += __shfl_xor(part, 1);
    part += __shfl_xor(part, 2);
    part += __shfl_xor(part, 4);
    part += __shfl_xor(part, 8);
    if (l == 0 && valid) score[c] = part + bp[0];
}

// POOL_SPLIT blocks per graph. Fused per-graph softmax (each block recomputes
// m,z over the graph's scores — L2-resident). Per-lane W column in 16 NAMED
// float4s; node agg row staged via LDS broadcast; 4 FMA chains; prefetch.
#define WLOAD(i) float4 wq##i = make_float4(We[(4*(i)+0)*NIN+lane], We[(4*(i)+1)*NIN+lane], \
                                            We[(4*(i)+2)*NIN+lane], We[(4*(i)+3)*NIN+lane]);
#define WSTEP(i) { float4 av = *(const float4*)&als[wv][4*(i)]; \
    e0 = fmaf(av.x, wq##i.x, e0); e1 = fmaf(av.y, wq##i.y, e1); \
    e2 = fmaf(av.z, wq##i.z, e2); e3 = fmaf(av.w, wq##i.w, e3); }

__global__ void __launch_bounds__(256)
k_pool(const ushort* __restrict__ agg16, const float* __restrict__ score,
       const float* __restrict__ We, const float* __restrict__ be,
       const int* __restrict__ gstart, const int* __restrict__ gend,
       float* __restrict__ out) {
    int g = blockIdx.x / POOL_SPLIT;
    int p = blockIdx.x % POOL_SPLIT;
    int tid = threadIdx.x;
    int wv = tid >> 6, lane = tid & 63;
    int s = gstart[g], e = gend[g];

    __shared__ float red[4];
    __shared__ float bc;

    float mx = -3.402823466e38f;
    for (int i = s + tid; i < e; i += 256) mx = fmaxf(mx, score[i]);
    #pragma unroll
    for (int off = 32; off > 0; off >>= 1) mx = fmaxf(mx, __shfl_xor(mx, off));
    if (lane == 0) red[wv] = mx;
    __syncthreads();
    if (tid == 0) bc = fmaxf(fmaxf(red[0], red[1]), fmaxf(red[2], red[3]));
    __syncthreads();
    float m = bc;
    __syncthreads();

    float sm = 0.0f;
    for (int i = s + tid; i < e; i += 256) sm += __expf(score[i] - m);
    sm = wave_reduce_sum(sm);
    if (lane == 0) red[wv] = sm;
    __syncthreads();
    if (tid == 0) bc = red[0] + red[1] + red[2] + red[3];
    __syncthreads();
    float invz = (bc > 0.0f) ? 1.0f / bc : 0.0f;

    WLOAD(0) WLOAD(1) WLOAD(2) WLOAD(3) WLOAD(4) WLOAD(5) WLOAD(6) WLOAD(7)
    WLOAD(8) WLOAD(9) WLOAD(10) WLOAD(11) WLOAD(12) WLOAD(13) WLOAD(14) WLOAD(15)
    float bj = be[lane];

    __shared__ float als[4][NIN];
    __shared__ float part[4][NIN];

    const int stride = POOL_SPLIT * 4;
    int n = s + p * 4 + wv;
    float acc = 0.0f;

    float a_cur = 0.0f, sw_cur = 0.0f;
    if (n < e) {
        a_cur = bf2f(agg16[(size_t)n * NIN + lane]);
        sw_cur = __expf(score[n] - m) * invz;
    }
    while (n < e) {
        int nn = n + stride;
        bool vn = nn < e;
        int ni = vn ? nn : n;
        float a_nxt = bf2f(agg16[(size_t)ni * NIN + lane]);   // prefetch
        float sw_nxt = __expf(score[ni] - m) * invz;

        als[wv][lane] = a_cur;
        float e0 = bj, e1 = 0.0f, e2 = 0.0f, e3 = 0.0f;
        WSTEP(0) WSTEP(1) WSTEP(2) WSTEP(3) WSTEP(4) WSTEP(5) WSTEP(6) WSTEP(7)
        WSTEP(8) WSTEP(9) WSTEP(10) WSTEP(11) WSTEP(12) WSTEP(13) WSTEP(14) WSTEP(15)
        float emb = fmaxf(e0 + e1 + e2 + e3, 0.0f);
        acc = fmaf(sw_cur, emb, acc);

        a_cur = a_nxt; sw_cur = sw_nxt;
        n = nn;
    }
    part[wv][lane] = acc;
    __syncthreads();
    if (wv == 0) {
        float r = part[0][lane] + part[1][lane] + part[2][lane] + part[3][lane];
        atomicAdd(&out[(size_t)g * NIN + lane], r);
    }
}

extern "C" void kernel_launch(void* const* d_in, const int* in_sizes, int n_in,
                              void* d_out, int out_size, void* d_ws, size_t ws_size,
                              hipStream_t stream) {
    const float* x  = (const float*)d_in[0];
    const float* We = (const float*)d_in[1];
    const float* be = (const float*)d_in[2];
    const float* Wp = (const float*)d_in[3];
    const float* bp = (const float*)d_in[4];
    const float* ew = (const float*)d_in[5];
    const int* eidx = (const int*)d_in[6];
    const int* seg  = (const int*)d_in[7];

    int N = in_sizes[0] / NIN;
    int E = in_sizes[5];
    const int* row = eidx;
    const int* col = eidx + E;

    char* w = (char*)d_ws;
    auto alloc = [&](size_t bytes) {
        char* p = w;
        w += (bytes + 255) & ~(size_t)255;
        return p;
    };
    float*          aggf    = (float*)alloc((size_t)N * NIN * sizeof(float));
    unsigned short* x16     = (unsigned short*)alloc((size_t)N * NIN * sizeof(short));
    unsigned short* agg16   = (unsigned short*)alloc((size_t)N * NIN * sizeof(short));
    float*          deg     = (float*)alloc((size_t)N * sizeof(float));
    int*            cnt     = (int*)  alloc((size_t)N * sizeof(int));
    unsigned int*   ell     = (unsigned int*)alloc((size_t)N * CAP * sizeof(unsigned int));
    int2*           ovf     = (int2*) alloc((size_t)E * sizeof(int2));
    int*            ovf_cnt = (int*)  alloc(256);
    float*          score   = (float*)alloc((size_t)N * sizeof(float));
    int*            gstart  = (int*)  alloc(GSEG * sizeof(int));
    int*            gend    = (int*)  alloc(GSEG * sizeof(int));
    float* out = (float*)d_out;

    int b = 256;
    int g_init   = (N * (NIN / 4) + b - 1) / b;
    int nchunks  = (E + b - 1) / b;
    int g_fill   = nchunks * 8;
    int g_nodes  = (N + b - 1) / b;
    int nwaves   = (N + 3) / 4;
    int g_gather = (nwaves + 3) / 4;

    k_init<<<g_init, b, 0, stream>>>((float4*)aggf, (ushort4*)x16, (const float4*)x,
                                     deg, cnt, out, gstart, gend, ovf_cnt, N);
    k_fill<<<g_fill, b, 0, stream>>>(row, col, ew, deg, cnt, ell, ovf, ovf_cnt, E);
    k_node<<<g_nodes, b, 0, stream>>>(deg, seg, gstart, gend, N);
    k_ovf<<<64, b, 0, stream>>>(ovf, ovf_cnt, deg, x16, aggf);
    k_gather<<<g_gather, b, 0, stream>>>(x16, deg, cnt, ell, aggf, agg16, Wp, bp, score, N);
    k_pool<<<GSEG * POOL_SPLIT, b, 0, stream>>>(agg16, score, We, be, gstart, gend, out);
}